// Round 9
// baseline (750.210 us; speedup 1.0000x reference)
//
#include <hip/hip_runtime.h>
#include <hip/hip_bf16.h>
#include <stdint.h>

typedef unsigned short ushort;
typedef unsigned int uint;
typedef unsigned char uchar;

#define N_NODES 100000
#define N_EDGES 1600000
#define KDIM 192      // 3 * 64 concatenated h_j
#define HIDDEN 512
#define NCHUNK 782    // ceil(N/128)
#define SDIM (KDIM*KDIM)
#define NPAIR 78      // 12*13/2 upper-triangle band pairs
#define PPB   9984    // uints per block partial: 78 frags * 128 uints
#define NSPLIT 8
#define LDT 194       // ushort stride of node-major LDS tile (192 + 2 pad)
#define NSLICE 256    // edge slices for LDS histogram
#define EPS (N_EDGES/NSLICE)   // 6250 edges per slice
#define NGRP 12500    // N_NODES/8 nibble groups
#define RSZ  12500    // nodes per region

typedef __attribute__((ext_vector_type(8))) short short8;
typedef __attribute__((ext_vector_type(4))) short short4v;
typedef __attribute__((ext_vector_type(4))) uint uint4v;
typedef __attribute__((ext_vector_type(4))) float float4v;
typedef __attribute__((ext_vector_type(2))) float float2v;
typedef __attribute__((ext_vector_type(2))) uint uint2v;

__device__ __forceinline__ float bf2f(ushort u){
    uint x = ((uint)u) << 16;
    return __builtin_bit_cast(float, x);
}
__device__ __forceinline__ float bflo(uint u){
    return __builtin_bit_cast(float, u << 16);
}
__device__ __forceinline__ float bfhi(uint u){
    return __builtin_bit_cast(float, u & 0xffff0000u);
}
__device__ __forceinline__ ushort f2bf(float f){
    uint u = __builtin_bit_cast(uint, f);
    u += 0x7fffu + ((u >> 16) & 1u);   // round-to-nearest-even
    return (ushort)(u >> 16);
}
// XCD id of the executing block (hwreg 20 = HW_REG_XCC_ID); used as a HINT only.
__device__ __forceinline__ int xcc_id(){
    int x;
    asm volatile("s_getreg_b32 %0, hwreg(20, 0, 4)" : "=s"(x));
    return x & 7;
}

// ---- 1. per-slice LDS nibble histogram + within-slice rank (NO global atomics) ----
__global__ __launch_bounds__(1024) void k_hist(const int* __restrict__ dst,
                                               uint* __restrict__ hist,
                                               uchar* __restrict__ rank8){
    __shared__ uint nib[NGRP];   // 50 KB
    int b = blockIdx.x, t = threadIdx.x;
    for (int g = t; g < NGRP; g += 1024) nib[g] = 0;
    __syncthreads();
    int e0 = b * EPS;
    for (int i = t; i < EPS; i += 1024){
        int e = e0 + i;
        int d = dst[e];
        uint sh = (uint)(d & 7) * 4;
        uint old = atomicAdd(&nib[d >> 3], 1u << sh);
        rank8[e] = (uchar)((old >> sh) & 0xf);
    }
    __syncthreads();
    for (int g = t; g < NGRP; g += 1024) hist[(size_t)b*NGRP + g] = nib[g];
}

// ---- 1b. chunk-local exclusive prefix over 16 slices (u8), chunk totals ----
__global__ void k_scanA(const uint* __restrict__ hist, uchar* __restrict__ pfx,
                        uchar* __restrict__ ctot){
    int g = blockIdx.x*256 + threadIdx.x;
    if (g >= NGRP) return;
    int y = blockIdx.y;
    uint r[8] = {};
    for (int b = y*16; b < y*16 + 16; ++b){
        uint v = hist[(size_t)b*NGRP + g];
        uint2v pk;
        pk[0] = r[0] | (r[1]<<8) | (r[2]<<16) | (r[3]<<24);
        pk[1] = r[4] | (r[5]<<8) | (r[6]<<16) | (r[7]<<24);
        *(uint2v*)(pfx + (size_t)b*N_NODES + g*8) = pk;
        #pragma unroll
        for (int k = 0; k < 8; ++k) r[k] += (v >> (4*k)) & 0xf;
    }
    uint2v pk;
    pk[0] = r[0] | (r[1]<<8) | (r[2]<<16) | (r[3]<<24);
    pk[1] = r[4] | (r[5]<<8) | (r[6]<<16) | (r[7]<<24);
    *(uint2v*)(ctot + (size_t)y*N_NODES + g*8) = pk;
}

// ---- 1c. scan chunk totals -> chunk bases (u8), deg, nrm ----
__global__ void k_scan2(const uchar* __restrict__ ctot, uchar* __restrict__ cbase,
                        int* __restrict__ deg, float* __restrict__ nrm){
    int g = blockIdx.x*256 + threadIdx.x;
    if (g >= NGRP) return;
    uint r[8] = {};
    for (int y = 0; y < 16; ++y){
        uint2v v = *(const uint2v*)(ctot + (size_t)y*N_NODES + g*8);
        uint2v pk;
        pk[0] = r[0] | (r[1]<<8) | (r[2]<<16) | (r[3]<<24);
        pk[1] = r[4] | (r[5]<<8) | (r[6]<<16) | (r[7]<<24);
        *(uint2v*)(cbase + (size_t)y*N_NODES + g*8) = pk;
        #pragma unroll
        for (int k = 0; k < 4; ++k) r[k] += (v[0] >> (8*k)) & 0xff;
        #pragma unroll
        for (int k = 0; k < 4; ++k) r[4+k] += (v[1] >> (8*k)) & 0xff;
    }
    #pragma unroll
    for (int k = 0; k < 8; ++k){
        int n = g*8 + k;
        deg[n] = (int)r[k];
        nrm[n] = rsqrtf((float)(r[k] > 0 ? r[k] : 1));
    }
}

// ---- 2. per-node CSR base (block scan + 1 atomic/block) ----
__global__ void k_rowptr(const int* __restrict__ deg, int* __restrict__ rowptr,
                         int* __restrict__ counter){
    __shared__ int sc[256];
    __shared__ int sbase;
    int t = threadIdx.x;
    int n = blockIdx.x * 256 + t;
    int d = (n < N_NODES) ? deg[n] : 0;
    sc[t] = d; __syncthreads();
    for (int off = 1; off < 256; off <<= 1){
        int v = 0;
        if (t >= off) v = sc[t - off];
        __syncthreads();
        sc[t] += v;
        __syncthreads();
    }
    int incl = sc[t];
    int total = sc[255];
    int excl = incl - d;
    if (t == 0) sbase = atomicAdd(counter, total);
    __syncthreads();
    if (n < N_NODES) rowptr[n] = sbase + excl;
}

// ---- 3. cast feats to bf16 pre-scaled by nrm ----
__global__ void k_cast(const float* __restrict__ feats, const float* __restrict__ nrm,
                       ushort* __restrict__ Hx){
    int i = blockIdx.x * 256 + threadIdx.x;   // float4 groups, 16 per node
    if (i < N_NODES * 16){
        float w = nrm[i >> 4];
        float4v v = ((const float4v*)feats)[i];
        short4v o;
        o[0] = (short)f2bf(v[0]*w); o[1] = (short)f2bf(v[1]*w);
        o[2] = (short)f2bf(v[2]*w); o[3] = (short)f2bf(v[3]*w);
        ((short4v*)Hx)[i] = o;
    }
}

// ---- 4. scatter: XCD-affine work-stealing over (region, slice) units ----
// Block's home region = xcc_id() (hint). Coverage is guaranteed even if the
// hint is garbage: after the home region's slices are exhausted, steal others.
__global__ __launch_bounds__(256) void k_scatter(const int* __restrict__ src,
                          const int* __restrict__ dst,
                          const int* __restrict__ rowptr, const uchar* __restrict__ pfx,
                          const uchar* __restrict__ cbase, const uchar* __restrict__ rank8,
                          int* __restrict__ rcnt, int* __restrict__ csr){
    __shared__ int sslice;
    int r = xcc_id();
    for (int k = 0; k < 8; ++k){
        int rg = (r + k) & 7;
        int lo = rg * RSZ, hi = lo + RSZ;
        while (true){
            __syncthreads();
            if (threadIdx.x == 0) sslice = atomicAdd(&rcnt[rg], 1);
            __syncthreads();
            int slice = sslice;
            if (slice >= NSLICE) break;
            const uchar* pr = pfx + (size_t)slice*N_NODES;
            const uchar* cb = cbase + (size_t)(slice >> 4)*N_NODES;
            int e0 = slice * EPS;
            for (int i = threadIdx.x; i < EPS; i += 256){
                int e = e0 + i;
                int d = dst[e];
                if (d >= lo && d < hi){
                    int pos = rowptr[d] + (int)cb[d] + (int)pr[d] + (int)rank8[e];
                    csr[pos] = src[e];
                }
            }
        }
    }
}

// ---- 5. aggregation: 8 lanes per edge row, dwordx4 gathers ----
template<bool WRITE_HS>
__global__ void k_agg(const ushort* __restrict__ inp,
                      ushort* __restrict__ H, int outoff,
                      ushort* __restrict__ Hs,
                      const int* __restrict__ rowptr, const int* __restrict__ deg,
                      const float* __restrict__ nrm, const int* __restrict__ csr){
    int node = (blockIdx.x << 2) + (threadIdx.x >> 6);
    int lane = threadIdx.x & 63;
    if (node >= N_NODES) return;
    int slot = lane >> 3;      // 0..7: edge slot
    int fb   = lane & 7;       // feature block (8 feats = 16B)
    int beg = rowptr[node];
    int d   = deg[node];
    float acc[8] = {};
    int i = 0;
    for (; i + 16 <= d; i += 16){
        int sA = csr[beg + i + slot];
        int sB = csr[beg + i + 8 + slot];
        uint4v vA = *(const uint4v*)(inp + (long)sA*64 + fb*8);
        uint4v vB = *(const uint4v*)(inp + (long)sB*64 + fb*8);
        #pragma unroll
        for (int p = 0; p < 4; ++p){
            acc[2*p]   += bflo(vA[p]); acc[2*p+1] += bfhi(vA[p]);
            acc[2*p]   += bflo(vB[p]); acc[2*p+1] += bfhi(vB[p]);
        }
    }
    if (i + 8 <= d){
        int sA = csr[beg + i + slot];
        uint4v vA = *(const uint4v*)(inp + (long)sA*64 + fb*8);
        #pragma unroll
        for (int p = 0; p < 4; ++p){
            acc[2*p]   += bflo(vA[p]); acc[2*p+1] += bfhi(vA[p]);
        }
        i += 8;
    }
    if (i + slot < d){
        int s = csr[beg + i + slot];
        uint4v v = *(const uint4v*)(inp + (long)s*64 + fb*8);
        #pragma unroll
        for (int p = 0; p < 4; ++p){
            acc[2*p]   += bflo(v[p]); acc[2*p+1] += bfhi(v[p]);
        }
    }
    // reduce across the 8 slots
    #pragma unroll
    for (int k = 0; k < 8; ++k){
        acc[k] += __shfl_xor(acc[k], 8);
        acc[k] += __shfl_xor(acc[k], 16);
        acc[k] += __shfl_xor(acc[k], 32);
    }
    if (slot == 0){
        float wn = nrm[node];
        short8 o;
        #pragma unroll
        for (int k = 0; k < 8; ++k) o[k] = (short)f2bf(wn * acc[k]);
        *(short8*)(H + (long)node*KDIM + outoff + fb*8) = o;
        if (WRITE_HS){
            float w2 = wn * wn;
            short8 o2;
            #pragma unroll
            for (int k = 0; k < 8; ++k) o2[k] = (short)f2bf(w2 * acc[k]);
            *(short8*)(Hs + (long)node*64 + fb*8) = o2;
        }
    }
}

// ---- 6. fold weights: MT[c][64j+d] = sum_k Wj[k,d] * fcW[c, 512j+k] ----
__global__ void k_prepM(const float* __restrict__ W0, const float* __restrict__ W1,
                        const float* __restrict__ W2, const float* __restrict__ fcW,
                        ushort* __restrict__ MT){
    int c  = blockIdx.x;        // 0..511
    int jd = threadIdx.x;       // 0..191
    int j = jd >> 6, d = jd & 63;
    const float* W  = (j == 0) ? W0 : (j == 1) ? W1 : W2;
    const float* fw = fcW + (long)c*1536 + j*512;
    float s = 0.f;
    #pragma unroll 4
    for (int k = 0; k < 512; ++k) s += W[k*64 + d] * fw[k];
    MT[c*KDIM + jd] = f2bf(s);
}

// ---- 6b. folded bias ----
__global__ void k_bias(const float* __restrict__ b0, const float* __restrict__ b1,
                       const float* __restrict__ b2, const float* __restrict__ fcW,
                       const float* __restrict__ fcb, float* __restrict__ Bc){
    int c = blockIdx.x*256 + threadIdx.x;
    if (c >= HIDDEN) return;
    const float* fw = fcW + (long)c*1536;
    float s = fcb[c];
    for (int k = 0; k < 512; ++k)
        s += b0[k]*fw[k] + b1[k]*fw[512+k] + b2[k]*fw[1024+k];
    Bc[c] = s;
}

// ---- 7. symmetric H^T H: node-major LDS, 78 upper-tri band pairs ----
template<int W>
__device__ __forceinline__ void do_pairs(const short8* frag, float4v* acc){
    int p = 0, c = 0;
    #pragma unroll
    for (int i = 0; i < 12; ++i)
        #pragma unroll
        for (int j = i; j < 12; ++j){
            if ((p & 3) == W){
                acc[c] = __builtin_amdgcn_mfma_f32_16x16x32_bf16(frag[i], frag[j], acc[c], 0,0,0);
                ++c;
            }
            ++p;
        }
}
template<int W>
__device__ __forceinline__ void store_pairs(const float4v* acc, uint* Pb, int lane){
    int p = 0, c = 0;
    #pragma unroll
    for (int i = 0; i < 12; ++i)
        #pragma unroll
        for (int j = i; j < 12; ++j){
            if ((p & 3) == W){
                uint2v v;
                v[0] = (uint)f2bf(acc[c][0]) | ((uint)f2bf(acc[c][1]) << 16);
                v[1] = (uint)f2bf(acc[c][2]) | ((uint)f2bf(acc[c][3]) << 16);
                *(uint2v*)(Pb + p*128 + lane*2) = v;
                ++c;
            }
            ++p;
        }
}

__global__ __launch_bounds__(256, 2) void k_hth(const ushort* __restrict__ H,
                                                uint* __restrict__ P,
                                                float* __restrict__ msum){
    __shared__ ushort Ts[128*LDT];   // 49664 B, node-major
    int t = threadIdx.x;
    int w = t >> 6, lane = t & 63;
    int m16 = lane & 15, quad = lane >> 4;
    int n0 = blockIdx.x * 128;
    #pragma unroll
    for (int it = 0; it < 12; ++it){
        int flat = it*256 + t;           // 128 rows * 24 segs
        int row = flat / 24, seg = flat - row*24;
        int gr = n0 + row;
        short8 v = {0,0,0,0,0,0,0,0};
        if (gr < N_NODES) v = *(const short8*)(H + (long)gr*KDIM + seg*8);
        *(short8*)(Ts + row*LDT + seg*8) = v;
    }
    __syncthreads();
    float4v acc[20] = {};
    #pragma unroll
    for (int kt = 0; kt < 4; ++kt){
        short8 frag[12];
        #pragma unroll
        for (int b = 0; b < 12; ++b){
            short8 f;
            #pragma unroll
            for (int j = 0; j < 8; ++j)
                f[j] = (short)Ts[(kt*32 + quad*8 + j)*LDT + b*16 + m16];
            frag[b] = f;
        }
        if      (w == 0) do_pairs<0>(frag, acc);
        else if (w == 1) do_pairs<1>(frag, acc);
        else if (w == 2) do_pairs<2>(frag, acc);
        else             do_pairs<3>(frag, acc);
    }
    // folded column sums (Ts untouched since staging)
    if (t < KDIM){
        float s = 0.f;
        #pragma unroll 4
        for (int n = 0; n < 128; ++n) s += bf2f(Ts[n*LDT + t]);
        atomicAdd(&msum[t], s);
    }
    uint* Pb = P + (long)blockIdx.x * PPB;
    if      (w == 0) store_pairs<0>(acc, Pb, lane);
    else if (w == 1) store_pairs<1>(acc, Pb, lane);
    else if (w == 2) store_pairs<2>(acc, Pb, lane);
    else             store_pairs<3>(acc, Pb, lane);
}

// ---- 8. split-K reduce of partials (coalesced) ----
__global__ void k_reduce(const uint* __restrict__ P, float* __restrict__ SP){
    int p = blockIdx.x * 256 + threadIdx.x;   // 0..9983
    int y = blockIdx.y;
    int b0 = y * 98, b1 = min(b0 + 98, NCHUNK);
    float lo = 0.f, hi = 0.f;
    for (int b = b0; b < b1; ++b){
        uint v = P[(long)b*PPB + p];
        lo += bf2f((ushort)(v & 0xffff));
        hi += bf2f((ushort)(v >> 16));
    }
    float2v o; o[0] = lo; o[1] = hi;
    *(float2v*)(SP + (long)y*(NPAIR*256) + p*2) = o;
}

// ---- 9. finalize covariance C (both triangles) from fragment layout ----
__global__ void k_finC(const float* __restrict__ SP, const float* __restrict__ msum,
                       float* __restrict__ C){
    int idx = blockIdx.x * 256 + threadIdx.x;   // 0..19967
    float s = 0.f;
    #pragma unroll
    for (int y = 0; y < NSPLIT; ++y) s += SP[(long)y*(NPAIR*256) + idx];
    int h = idx & 1, pu = idx >> 1;
    int p = pu >> 7, rem = pu & 127;
    int l = rem >> 1, u = rem & 1;
    int r = u*2 + h;
    int pi = 0, pj = 0, off = 0;
    #pragma unroll
    for (int k = 0; k < 12; ++k){
        int len = 12 - k;
        if (p >= off && p < off + len){ pi = k; pj = k + (p - off); }
        off += len;
    }
    int m = pi*16 + (l >> 4)*4 + r;
    int n = pj*16 + (l & 15);
    const float invN = 1.f / (float)N_NODES;
    float v = s*invN - (msum[m]*invN)*(msum[n]*invN);
    C[m*KDIM + n] = v;
    C[n*KDIM + m] = v;
}

// ---- 10. V[c] = C @ M_c ----
__global__ void k_cv(const float* __restrict__ C, const ushort* __restrict__ MT,
                     float* __restrict__ V){
    int c = blockIdx.x, d = threadIdx.x;  // 512 x 192
    const ushort* mt = MT + c*KDIM;
    float s = 0.f;
    #pragma unroll 4
    for (int dp = 0; dp < KDIM; ++dp)
        s += bf2f(mt[dp]) * C[dp*KDIM + d];
    V[c*KDIM + d] = s;
}

// ---- 11. BN solve: r_c, cvec ----
__global__ void k_solve2(const float* __restrict__ V, const ushort* __restrict__ MT,
                         const float* __restrict__ msum, const float* __restrict__ Bc,
                         const float* __restrict__ gamma, const float* __restrict__ beta,
                         const float* __restrict__ q,
                         float* __restrict__ rr, float* __restrict__ cvec){
    __shared__ float tmp[HIDDEN];
    int c = threadIdx.x;  // 0..511
    const float invN = 1.f / (float)N_NODES;
    float mu = Bc[c], var = 0.f;
    const ushort* mt = MT + c*KDIM;
    const float* vc = V + c*KDIM;
    #pragma unroll 4
    for (int d = 0; d < KDIM; ++d){
        float m = bf2f(mt[d]);
        mu  += msum[d]*invN * m;
        var += vc[d] * m;
    }
    float r = gamma[c] * rsqrtf(var + 1e-5f);
    rr[c] = r;
    tmp[c] = r * (Bc[c] - mu) + beta[c];
    __syncthreads();
    if (c < 64){
        float s = 0.f;
        #pragma unroll
        for (int k = 0; k < 8; ++k) s += q[k] * tmp[k*64 + c];
        cvec[c] = s;
    }
}

// ---- 12. fold rho into M: GT[o][d] = sum_k q_k r_{k64+o} MT[k64+o][d] ----
__global__ void k_buildG(const ushort* __restrict__ MT, const float* __restrict__ rr,
                         const float* __restrict__ q, ushort* __restrict__ GT){
    int o = blockIdx.x, d = threadIdx.x;  // 64 x 192
    float s = 0.f;
    #pragma unroll
    for (int k = 0; k < 8; ++k)
        s += q[k] * rr[k*64 + o] * bf2f(MT[(k*64 + o)*KDIM + d]);
    GT[o*KDIM + d] = f2bf(s);
}

// ---- 13. out = H @ GT^T + cvec ----
#define LDA 200
__global__ __launch_bounds__(256) void k_outgemm(const ushort* __restrict__ H,
                                                 const ushort* __restrict__ GT,
                                                 const float* __restrict__ cvec,
                                                 float* __restrict__ out){
    __shared__ ushort As[128*LDA];
    __shared__ ushort Gs[64*LDA];
    int t = threadIdx.x;
    int n0 = blockIdx.x * 128;
    int w = t >> 6, lane = t & 63;
    int m16 = lane & 15, quad = lane >> 4;
    int wr = w * 32;
    float4v acc[2][4] = {};
    #pragma unroll
    for (int it = 0; it < 12; ++it){
        int flat = it*256 + t;               // 128 rows * 24 segs
        int row = flat / 24, seg = flat - row*24;
        int gr = n0 + row;
        short8 v = {0,0,0,0,0,0,0,0};
        if (gr < N_NODES) v = *(const short8*)(H + (long)gr*KDIM + seg*8);
        *(short8*)(As + row*LDA + seg*8) = v;
    }
    #pragma unroll
    for (int it = 0; it < 6; ++it){
        int flat = it*256 + t;               // 64 rows * 24 segs
        int row = flat / 24, seg = flat - row*24;
        short8 v = *(const short8*)(GT + row*KDIM + seg*8);
        *(short8*)(Gs + row*LDA + seg*8) = v;
    }
    __syncthreads();
    #pragma unroll
    for (int kk = 0; kk < 192; kk += 32){
        short8 af[2], bf[4];
        #pragma unroll
        for (int i = 0; i < 2; ++i)
            af[i] = *(const short8*)(As + (wr + i*16 + m16)*LDA + kk + quad*8);
        #pragma unroll
        for (int j = 0; j < 4; ++j)
            bf[j] = *(const short8*)(Gs + (j*16 + m16)*LDA + kk + quad*8);
        #pragma unroll
        for (int i = 0; i < 2; ++i)
            #pragma unroll
            for (int j = 0; j < 4; ++j)
                acc[i][j] = __builtin_amdgcn_mfma_f32_16x16x32_bf16(af[i], bf[j], acc[i][j], 0,0,0);
    }
    #pragma unroll
    for (int i = 0; i < 2; ++i)
        #pragma unroll
        for (int j = 0; j < 4; ++j)
            #pragma unroll
            for (int r = 0; r < 4; ++r){
                int rowg = n0 + wr + i*16 + quad*4 + r;
                int o = j*16 + m16;
                if (rowg < N_NODES) out[(long)rowg*64 + o] = acc[i][j][r] + cvec[o];
            }
}

extern "C" void kernel_launch(void* const* d_in, const int* in_sizes, int n_in,
                              void* d_out, int out_size, void* d_ws, size_t ws_size,
                              hipStream_t stream) {
    const float* feats = (const float*)d_in[0];
    const int*   src   = (const int*)  d_in[1];
    const int*   dst   = (const int*)  d_in[2];
    const float* W0    = (const float*)d_in[3];
    const float* b0    = (const float*)d_in[4];
    const float* W1    = (const float*)d_in[5];
    const float* b1    = (const float*)d_in[6];
    const float* W2    = (const float*)d_in[7];
    const float* b2    = (const float*)d_in[8];
    const float* fcW   = (const float*)d_in[9];
    const float* fcb   = (const float*)d_in[10];
    const float* gamma = (const float*)d_in[11];
    const float* beta  = (const float*)d_in[12];
    const float* q     = (const float*)d_in[13];
    float* out = (float*)d_out;

    char* ws = (char*)d_ws;
    size_t off = 0;
    auto alloc = [&](size_t bytes) -> char* {
        char* p = ws + off;
        off = (off + bytes + 511) & ~(size_t)511;
        return p;
    };
    uint*   hist    = (uint*)  alloc((size_t)NSLICE * NGRP * 4);
    uchar*  pfx     = (uchar*) alloc((size_t)NSLICE * N_NODES);
    uchar*  ctot    = (uchar*) alloc((size_t)16 * N_NODES);
    uchar*  cbase   = (uchar*) alloc((size_t)16 * N_NODES);
    uchar*  rank8   = (uchar*) alloc((size_t)N_EDGES);
    int*    deg     = (int*)   alloc((size_t)N_NODES * 4);
    int*    rowptr  = (int*)   alloc((size_t)N_NODES * 4);
    float*  nrm     = (float*) alloc((size_t)N_NODES * 4);
    int*    counter = (int*)   alloc(256);       // [0]=rowptr base, [8..15]=rcnt
    int*    csr     = (int*)   alloc((size_t)N_EDGES * 4);
    ushort* Hx      = (ushort*)alloc((size_t)N_NODES * 64 * 2);
    ushort* HsB     = (ushort*)alloc((size_t)N_NODES * 64 * 2);
    ushort* H       = (ushort*)alloc((size_t)N_NODES * KDIM * 2);
    ushort* MT      = (ushort*)alloc((size_t)HIDDEN * KDIM * 2);
    float*  Bc      = (float*) alloc((size_t)HIDDEN * 4);
    float*  msum    = (float*) alloc((size_t)KDIM * 4);
    uint*   P       = (uint*)  alloc((size_t)NCHUNK * PPB * 4);
    float*  SP      = (float*) alloc((size_t)NSPLIT * NPAIR * 256 * 4);
    float*  C       = (float*) alloc((size_t)SDIM * 4);
    float*  V       = (float*) alloc((size_t)HIDDEN * KDIM * 4);
    float*  rr      = (float*) alloc((size_t)HIDDEN * 4);
    float*  cvec    = (float*) alloc((size_t)64 * 4);
    ushort* GT      = (ushort*)alloc((size_t)64 * KDIM * 2);
    (void)ws_size; (void)n_in; (void)in_sizes; (void)out_size;

    hipMemsetAsync(counter, 0, 256, stream);
    hipMemsetAsync(msum, 0, (size_t)KDIM * 4, stream);

    k_hist  <<<NSLICE, 1024, 0, stream>>>(dst, hist, rank8);
    dim3 saGrid((NGRP + 255)/256, 16);
    k_scanA <<<saGrid, 256, 0, stream>>>(hist, pfx, ctot);
    k_scan2 <<<(NGRP + 255)/256, 256, 0, stream>>>(ctot, cbase, deg, nrm);
    k_rowptr<<<(N_NODES + 255)/256, 256, 0, stream>>>(deg, rowptr, counter);
    k_cast  <<<(N_NODES*16 + 255)/256, 256, 0, stream>>>(feats, nrm, Hx);
    k_scatter<<<2048, 256, 0, stream>>>(src, dst, rowptr, pfx, cbase, rank8,
                                        counter + 8, csr);

    int aggGrid = (N_NODES + 3) / 4;
    k_agg<true> <<<aggGrid, 256, 0, stream>>>(Hx,  H, 0,   HsB, rowptr, deg, nrm, csr);
    k_agg<true> <<<aggGrid, 256, 0, stream>>>(HsB, H, 64,  Hx,  rowptr, deg, nrm, csr);
    k_agg<false><<<aggGrid, 256, 0, stream>>>(Hx,  H, 128, HsB, rowptr, deg, nrm, csr);

    k_prepM<<<HIDDEN, KDIM, 0, stream>>>(W0, W1, W2, fcW, MT);
    k_bias <<<2, 256, 0, stream>>>(b0, b1, b2, fcW, fcb, Bc);

    k_hth   <<<NCHUNK, 256, 0, stream>>>(H, P, msum);
    dim3 rGrid(PPB/256, NSPLIT);
    k_reduce<<<rGrid, 256, 0, stream>>>(P, SP);
    k_finC  <<<NPAIR, 256, 0, stream>>>(SP, msum, C);
    k_cv    <<<HIDDEN, KDIM, 0, stream>>>(C, MT, V);
    k_solve2<<<1, HIDDEN, 0, stream>>>(V, MT, msum, Bc, gamma, beta, q, rr, cvec);
    k_buildG<<<64, KDIM, 0, stream>>>(MT, rr, q, GT);

    k_outgemm<<<NCHUNK, 256, 0, stream>>>(H, GT, cvec, out);
}

// Round 10
// 533.752 us; speedup vs baseline: 1.4055x; 1.4055x over previous
//
#include <hip/hip_runtime.h>
#include <hip/hip_bf16.h>
#include <stdint.h>

typedef unsigned short ushort;
typedef unsigned int uint;
typedef unsigned char uchar;

#define N_NODES 100000
#define N_EDGES 1600000
#define KDIM 192      // 3 * 64 concatenated h_j
#define HIDDEN 512
#define NCHUNK 782    // ceil(N/128)
#define SDIM (KDIM*KDIM)
#define NPAIR 78      // 12*13/2 upper-triangle band pairs
#define PPB   9984    // uints per block partial: 78 frags * 128 uints
#define NSPLIT 8
#define LDT 194       // ushort stride of node-major LDS tile (192 + 2 pad)
#define NSLICE 256    // edge slices for LDS histogram
#define EPS (N_EDGES/NSLICE)   // 6250 edges per slice
#define NGRP 12500    // N_NODES/8 nibble groups

typedef __attribute__((ext_vector_type(8))) short short8;
typedef __attribute__((ext_vector_type(4))) short short4v;
typedef __attribute__((ext_vector_type(4))) uint uint4v;
typedef __attribute__((ext_vector_type(4))) float float4v;
typedef __attribute__((ext_vector_type(2))) float float2v;
typedef __attribute__((ext_vector_type(2))) uint uint2v;

__device__ __forceinline__ float bf2f(ushort u){
    uint x = ((uint)u) << 16;
    return __builtin_bit_cast(float, x);
}
__device__ __forceinline__ float bflo(uint u){
    return __builtin_bit_cast(float, u << 16);
}
__device__ __forceinline__ float bfhi(uint u){
    return __builtin_bit_cast(float, u & 0xffff0000u);
}
__device__ __forceinline__ ushort f2bf(float f){
    uint u = __builtin_bit_cast(uint, f);
    u += 0x7fffu + ((u >> 16) & 1u);   // round-to-nearest-even
    return (ushort)(u >> 16);
}

// ---- 1. per-slice LDS nibble histogram + within-slice rank (NO global atomics) ----
__global__ __launch_bounds__(1024) void k_hist(const int* __restrict__ dst,
                                               uint* __restrict__ hist,
                                               uchar* __restrict__ rank8){
    __shared__ uint nib[NGRP];   // 50 KB
    int b = blockIdx.x, t = threadIdx.x;
    for (int g = t; g < NGRP; g += 1024) nib[g] = 0;
    __syncthreads();
    int e0 = b * EPS;
    for (int i = t; i < EPS; i += 1024){
        int e = e0 + i;
        int d = dst[e];
        uint sh = (uint)(d & 7) * 4;
        uint old = atomicAdd(&nib[d >> 3], 1u << sh);
        rank8[e] = (uchar)((old >> sh) & 0xf);
    }
    __syncthreads();
    for (int g = t; g < NGRP; g += 1024) hist[(size_t)b*NGRP + g] = nib[g];
}

// ---- 1b. chunk-local exclusive prefix over 16 slices (u8), chunk totals ----
__global__ void k_scanA(const uint* __restrict__ hist, uchar* __restrict__ pfx,
                        uchar* __restrict__ ctot){
    int g = blockIdx.x*256 + threadIdx.x;
    if (g >= NGRP) return;
    int y = blockIdx.y;
    uint r[8] = {};
    for (int b = y*16; b < y*16 + 16; ++b){
        uint v = hist[(size_t)b*NGRP + g];
        uint2v pk;
        pk[0] = r[0] | (r[1]<<8) | (r[2]<<16) | (r[3]<<24);
        pk[1] = r[4] | (r[5]<<8) | (r[6]<<16) | (r[7]<<24);
        *(uint2v*)(pfx + (size_t)b*N_NODES + g*8) = pk;
        #pragma unroll
        for (int k = 0; k < 8; ++k) r[k] += (v >> (4*k)) & 0xf;
    }
    uint2v pk;
    pk[0] = r[0] | (r[1]<<8) | (r[2]<<16) | (r[3]<<24);
    pk[1] = r[4] | (r[5]<<8) | (r[6]<<16) | (r[7]<<24);
    *(uint2v*)(ctot + (size_t)y*N_NODES + g*8) = pk;
}

// ---- 1c. scan chunk totals -> chunk bases (u8), deg, nrm ----
__global__ void k_scan2(const uchar* __restrict__ ctot, uchar* __restrict__ cbase,
                        int* __restrict__ deg, float* __restrict__ nrm){
    int g = blockIdx.x*256 + threadIdx.x;
    if (g >= NGRP) return;
    uint r[8] = {};
    for (int y = 0; y < 16; ++y){
        uint2v v = *(const uint2v*)(ctot + (size_t)y*N_NODES + g*8);
        uint2v pk;
        pk[0] = r[0] | (r[1]<<8) | (r[2]<<16) | (r[3]<<24);
        pk[1] = r[4] | (r[5]<<8) | (r[6]<<16) | (r[7]<<24);
        *(uint2v*)(cbase + (size_t)y*N_NODES + g*8) = pk;
        #pragma unroll
        for (int k = 0; k < 4; ++k) r[k] += (v[0] >> (8*k)) & 0xff;
        #pragma unroll
        for (int k = 0; k < 4; ++k) r[4+k] += (v[1] >> (8*k)) & 0xff;
    }
    #pragma unroll
    for (int k = 0; k < 8; ++k){
        int n = g*8 + k;
        deg[n] = (int)r[k];
        nrm[n] = rsqrtf((float)(r[k] > 0 ? r[k] : 1));
    }
}

// ---- 2. per-node CSR base (block scan + 1 atomic/block) ----
__global__ void k_rowptr(const int* __restrict__ deg, int* __restrict__ rowptr,
                         int* __restrict__ counter){
    __shared__ int sc[256];
    __shared__ int sbase;
    int t = threadIdx.x;
    int n = blockIdx.x * 256 + t;
    int d = (n < N_NODES) ? deg[n] : 0;
    sc[t] = d; __syncthreads();
    for (int off = 1; off < 256; off <<= 1){
        int v = 0;
        if (t >= off) v = sc[t - off];
        __syncthreads();
        sc[t] += v;
        __syncthreads();
    }
    int incl = sc[t];
    int total = sc[255];
    int excl = incl - d;
    if (t == 0) sbase = atomicAdd(counter, total);
    __syncthreads();
    if (n < N_NODES) rowptr[n] = sbase + excl;
}

// ---- 3. cast feats to bf16 pre-scaled by nrm ----
__global__ void k_cast(const float* __restrict__ feats, const float* __restrict__ nrm,
                       ushort* __restrict__ Hx){
    int i = blockIdx.x * 256 + threadIdx.x;   // float4 groups, 16 per node
    if (i < N_NODES * 16){
        float w = nrm[i >> 4];
        float4v v = ((const float4v*)feats)[i];
        short4v o;
        o[0] = (short)f2bf(v[0]*w); o[1] = (short)f2bf(v[1]*w);
        o[2] = (short)f2bf(v[2]*w); o[3] = (short)f2bf(v[3]*w);
        ((short4v*)Hx)[i] = o;
    }
}

// ---- 4. scatter edges into CSR: static 8-pass region partition (best known) ----
__global__ void k_scatter(const int* __restrict__ src, const int* __restrict__ dst,
                          const int* __restrict__ rowptr, const uchar* __restrict__ pfx,
                          const uchar* __restrict__ cbase, const uchar* __restrict__ rank8,
                          int* __restrict__ csr){
    int b = blockIdx.x;
    int region = b & 7;
    int slice  = b >> 3;
    int lo = region * (N_NODES/8), hi = lo + (N_NODES/8);
    int e0 = slice * EPS;
    const uchar* pr = pfx + (size_t)slice*N_NODES;
    const uchar* cb = cbase + (size_t)(slice >> 4)*N_NODES;
    for (int i = threadIdx.x; i < EPS; i += 256){
        int e = e0 + i;
        int d = dst[e];
        if (d >= lo && d < hi){
            int pos = rowptr[d] + (int)cb[d] + (int)pr[d] + (int)rank8[e];
            csr[pos] = src[e];
        }
    }
}

// ---- 5. aggregation: 2 nodes per wave (half-wave each), dwordx4 gathers ----
// half-wave: slot = (lane&31)>>3 (4 edge slots), fb = lane&7 (8 feats=16B)
template<bool WRITE_HS>
__global__ void k_agg(const ushort* __restrict__ inp,
                      ushort* __restrict__ H, int outoff,
                      ushort* __restrict__ Hs,
                      const int* __restrict__ rowptr, const int* __restrict__ deg,
                      const float* __restrict__ nrm, const int* __restrict__ csr){
    int node = (blockIdx.x << 3) + (threadIdx.x >> 5);
    int lane = threadIdx.x & 63;
    if (node >= N_NODES) return;
    int slot = (lane & 31) >> 3;   // 0..3
    int fb   = lane & 7;
    int beg = rowptr[node];
    int d   = deg[node];
    float acc[8] = {};
    int i = 0;
    for (; i + 8 <= d; i += 8){
        int sA = csr[beg + i + slot];
        int sB = csr[beg + i + 4 + slot];
        uint4v vA = *(const uint4v*)(inp + (long)sA*64 + fb*8);
        uint4v vB = *(const uint4v*)(inp + (long)sB*64 + fb*8);
        #pragma unroll
        for (int p = 0; p < 4; ++p){
            acc[2*p]   += bflo(vA[p]); acc[2*p+1] += bfhi(vA[p]);
            acc[2*p]   += bflo(vB[p]); acc[2*p+1] += bfhi(vB[p]);
        }
    }
    if (i + 4 <= d){
        int sA = csr[beg + i + slot];
        uint4v vA = *(const uint4v*)(inp + (long)sA*64 + fb*8);
        #pragma unroll
        for (int p = 0; p < 4; ++p){
            acc[2*p]   += bflo(vA[p]); acc[2*p+1] += bfhi(vA[p]);
        }
        i += 4;
    }
    if (i + slot < d){
        int s = csr[beg + i + slot];
        uint4v v = *(const uint4v*)(inp + (long)s*64 + fb*8);
        #pragma unroll
        for (int p = 0; p < 4; ++p){
            acc[2*p]   += bflo(v[p]); acc[2*p+1] += bfhi(v[p]);
        }
    }
    // reduce across the 4 slots (within half-wave)
    #pragma unroll
    for (int k = 0; k < 8; ++k){
        acc[k] += __shfl_xor(acc[k], 8);
        acc[k] += __shfl_xor(acc[k], 16);
    }
    if (slot == 0){
        float wn = nrm[node];
        short8 o;
        #pragma unroll
        for (int k = 0; k < 8; ++k) o[k] = (short)f2bf(wn * acc[k]);
        *(short8*)(H + (long)node*KDIM + outoff + fb*8) = o;
        if (WRITE_HS){
            float w2 = wn * wn;
            short8 o2;
            #pragma unroll
            for (int k = 0; k < 8; ++k) o2[k] = (short)f2bf(w2 * acc[k]);
            *(short8*)(Hs + (long)node*64 + fb*8) = o2;
        }
    }
}

// ---- 6. fold weights: MT[c][64j+d] = sum_k Wj[k,d] * fcW[c, 512j+k] ----
__global__ void k_prepM(const float* __restrict__ W0, const float* __restrict__ W1,
                        const float* __restrict__ W2, const float* __restrict__ fcW,
                        ushort* __restrict__ MT){
    int c  = blockIdx.x;        // 0..511
    int jd = threadIdx.x;       // 0..191
    int j = jd >> 6, d = jd & 63;
    const float* W  = (j == 0) ? W0 : (j == 1) ? W1 : W2;
    const float* fw = fcW + (long)c*1536 + j*512;
    float s = 0.f;
    #pragma unroll 4
    for (int k = 0; k < 512; ++k) s += W[k*64 + d] * fw[k];
    MT[c*KDIM + jd] = f2bf(s);
}

// ---- 6b. folded bias ----
__global__ void k_bias(const float* __restrict__ b0, const float* __restrict__ b1,
                       const float* __restrict__ b2, const float* __restrict__ fcW,
                       const float* __restrict__ fcb, float* __restrict__ Bc){
    int c = blockIdx.x*256 + threadIdx.x;
    if (c >= HIDDEN) return;
    const float* fw = fcW + (long)c*1536;
    float s = fcb[c];
    for (int k = 0; k < 512; ++k)
        s += b0[k]*fw[k] + b1[k]*fw[512+k] + b2[k]*fw[1024+k];
    Bc[c] = s;
}

// ---- 7. symmetric H^T H: node-major LDS, 78 upper-tri band pairs ----
template<int W>
__device__ __forceinline__ void do_pairs(const short8* frag, float4v* acc){
    int p = 0, c = 0;
    #pragma unroll
    for (int i = 0; i < 12; ++i)
        #pragma unroll
        for (int j = i; j < 12; ++j){
            if ((p & 3) == W){
                acc[c] = __builtin_amdgcn_mfma_f32_16x16x32_bf16(frag[i], frag[j], acc[c], 0,0,0);
                ++c;
            }
            ++p;
        }
}
template<int W>
__device__ __forceinline__ void store_pairs(const float4v* acc, uint* Pb, int lane){
    int p = 0, c = 0;
    #pragma unroll
    for (int i = 0; i < 12; ++i)
        #pragma unroll
        for (int j = i; j < 12; ++j){
            if ((p & 3) == W){
                uint2v v;
                v[0] = (uint)f2bf(acc[c][0]) | ((uint)f2bf(acc[c][1]) << 16);
                v[1] = (uint)f2bf(acc[c][2]) | ((uint)f2bf(acc[c][3]) << 16);
                *(uint2v*)(Pb + p*128 + lane*2) = v;
                ++c;
            }
            ++p;
        }
}

__global__ __launch_bounds__(256, 2) void k_hth(const ushort* __restrict__ H,
                                                uint* __restrict__ P,
                                                float* __restrict__ msum){
    __shared__ ushort Ts[128*LDT];   // 49664 B, node-major
    int t = threadIdx.x;
    int w = t >> 6, lane = t & 63;
    int m16 = lane & 15, quad = lane >> 4;
    int n0 = blockIdx.x * 128;
    #pragma unroll
    for (int it = 0; it < 12; ++it){
        int flat = it*256 + t;           // 128 rows * 24 segs
        int row = flat / 24, seg = flat - row*24;
        int gr = n0 + row;
        short8 v = {0,0,0,0,0,0,0,0};
        if (gr < N_NODES) v = *(const short8*)(H + (long)gr*KDIM + seg*8);
        *(short8*)(Ts + row*LDT + seg*8) = v;
    }
    __syncthreads();
    float4v acc[20] = {};
    #pragma unroll
    for (int kt = 0; kt < 4; ++kt){
        short8 frag[12];
        #pragma unroll
        for (int b = 0; b < 12; ++b){
            short8 f;
            #pragma unroll
            for (int j = 0; j < 8; ++j)
                f[j] = (short)Ts[(kt*32 + quad*8 + j)*LDT + b*16 + m16];
            frag[b] = f;
        }
        if      (w == 0) do_pairs<0>(frag, acc);
        else if (w == 1) do_pairs<1>(frag, acc);
        else if (w == 2) do_pairs<2>(frag, acc);
        else             do_pairs<3>(frag, acc);
    }
    // folded column sums (Ts untouched since staging)
    if (t < KDIM){
        float s = 0.f;
        #pragma unroll 4
        for (int n = 0; n < 128; ++n) s += bf2f(Ts[n*LDT + t]);
        atomicAdd(&msum[t], s);
    }
    uint* Pb = P + (long)blockIdx.x * PPB;
    if      (w == 0) store_pairs<0>(acc, Pb, lane);
    else if (w == 1) store_pairs<1>(acc, Pb, lane);
    else if (w == 2) store_pairs<2>(acc, Pb, lane);
    else             store_pairs<3>(acc, Pb, lane);
}

// ---- 8. split-K reduce of partials (coalesced) ----
__global__ void k_reduce(const uint* __restrict__ P, float* __restrict__ SP){
    int p = blockIdx.x * 256 + threadIdx.x;   // 0..9983
    int y = blockIdx.y;
    int b0 = y * 98, b1 = min(b0 + 98, NCHUNK);
    float lo = 0.f, hi = 0.f;
    for (int b = b0; b < b1; ++b){
        uint v = P[(long)b*PPB + p];
        lo += bf2f((ushort)(v & 0xffff));
        hi += bf2f((ushort)(v >> 16));
    }
    float2v o; o[0] = lo; o[1] = hi;
    *(float2v*)(SP + (long)y*(NPAIR*256) + p*2) = o;
}

// ---- 9. finalize covariance C (both triangles) from fragment layout ----
__global__ void k_finC(const float* __restrict__ SP, const float* __restrict__ msum,
                       float* __restrict__ C){
    int idx = blockIdx.x * 256 + threadIdx.x;   // 0..19967
    float s = 0.f;
    #pragma unroll
    for (int y = 0; y < NSPLIT; ++y) s += SP[(long)y*(NPAIR*256) + idx];
    int h = idx & 1, pu = idx >> 1;
    int p = pu >> 7, rem = pu & 127;
    int l = rem >> 1, u = rem & 1;
    int r = u*2 + h;
    int pi = 0, pj = 0, off = 0;
    #pragma unroll
    for (int k = 0; k < 12; ++k){
        int len = 12 - k;
        if (p >= off && p < off + len){ pi = k; pj = k + (p - off); }
        off += len;
    }
    int m = pi*16 + (l >> 4)*4 + r;
    int n = pj*16 + (l & 15);
    const float invN = 1.f / (float)N_NODES;
    float v = s*invN - (msum[m]*invN)*(msum[n]*invN);
    C[m*KDIM + n] = v;
    C[n*KDIM + m] = v;
}

// ---- 10. V[c] = C @ M_c ----
__global__ void k_cv(const float* __restrict__ C, const ushort* __restrict__ MT,
                     float* __restrict__ V){
    int c = blockIdx.x, d = threadIdx.x;  // 512 x 192
    const ushort* mt = MT + c*KDIM;
    float s = 0.f;
    #pragma unroll 4
    for (int dp = 0; dp < KDIM; ++dp)
        s += bf2f(mt[dp]) * C[dp*KDIM + d];
    V[c*KDIM + d] = s;
}

// ---- 11. BN solve: r_c, cvec ----
__global__ void k_solve2(const float* __restrict__ V, const ushort* __restrict__ MT,
                         const float* __restrict__ msum, const float* __restrict__ Bc,
                         const float* __restrict__ gamma, const float* __restrict__ beta,
                         const float* __restrict__ q,
                         float* __restrict__ rr, float* __restrict__ cvec){
    __shared__ float tmp[HIDDEN];
    int c = threadIdx.x;  // 0..511
    const float invN = 1.f / (float)N_NODES;
    float mu = Bc[c], var = 0.f;
    const ushort* mt = MT + c*KDIM;
    const float* vc = V + c*KDIM;
    #pragma unroll 4
    for (int d = 0; d < KDIM; ++d){
        float m = bf2f(mt[d]);
        mu  += msum[d]*invN * m;
        var += vc[d] * m;
    }
    float r = gamma[c] * rsqrtf(var + 1e-5f);
    rr[c] = r;
    tmp[c] = r * (Bc[c] - mu) + beta[c];
    __syncthreads();
    if (c < 64){
        float s = 0.f;
        #pragma unroll
        for (int k = 0; k < 8; ++k) s += q[k] * tmp[k*64 + c];
        cvec[c] = s;
    }
}

// ---- 12. fold rho into M: GT[o][d] = sum_k q_k r_{k64+o} MT[k64+o][d] ----
__global__ void k_buildG(const ushort* __restrict__ MT, const float* __restrict__ rr,
                         const float* __restrict__ q, ushort* __restrict__ GT){
    int o = blockIdx.x, d = threadIdx.x;  // 64 x 192
    float s = 0.f;
    #pragma unroll
    for (int k = 0; k < 8; ++k)
        s += q[k] * rr[k*64 + o] * bf2f(MT[(k*64 + o)*KDIM + d]);
    GT[o*KDIM + d] = f2bf(s);
}

// ---- 13. out = H @ GT^T + cvec ----
#define LDA 200
__global__ __launch_bounds__(256) void k_outgemm(const ushort* __restrict__ H,
                                                 const ushort* __restrict__ GT,
                                                 const float* __restrict__ cvec,
                                                 float* __restrict__ out){
    __shared__ ushort As[128*LDA];
    __shared__ ushort Gs[64*LDA];
    int t = threadIdx.x;
    int n0 = blockIdx.x * 128;
    int w = t >> 6, lane = t & 63;
    int m16 = lane & 15, quad = lane >> 4;
    int wr = w * 32;
    float4v acc[2][4] = {};
    #pragma unroll
    for (int it = 0; it < 12; ++it){
        int flat = it*256 + t;               // 128 rows * 24 segs
        int row = flat / 24, seg = flat - row*24;
        int gr = n0 + row;
        short8 v = {0,0,0,0,0,0,0,0};
        if (gr < N_NODES) v = *(const short8*)(H + (long)gr*KDIM + seg*8);
        *(short8*)(As + row*LDA + seg*8) = v;
    }
    #pragma unroll
    for (int it = 0; it < 6; ++it){
        int flat = it*256 + t;               // 64 rows * 24 segs
        int row = flat / 24, seg = flat - row*24;
        short8 v = *(const short8*)(GT + row*KDIM + seg*8);
        *(short8*)(Gs + row*LDA + seg*8) = v;
    }
    __syncthreads();
    #pragma unroll
    for (int kk = 0; kk < 192; kk += 32){
        short8 af[2], bf[4];
        #pragma unroll
        for (int i = 0; i < 2; ++i)
            af[i] = *(const short8*)(As + (wr + i*16 + m16)*LDA + kk + quad*8);
        #pragma unroll
        for (int j = 0; j < 4; ++j)
            bf[j] = *(const short8*)(Gs + (j*16 + m16)*LDA + kk + quad*8);
        #pragma unroll
        for (int i = 0; i < 2; ++i)
            #pragma unroll
            for (int j = 0; j < 4; ++j)
                acc[i][j] = __builtin_amdgcn_mfma_f32_16x16x32_bf16(af[i], bf[j], acc[i][j], 0,0,0);
    }
    #pragma unroll
    for (int i = 0; i < 2; ++i)
        #pragma unroll
        for (int j = 0; j < 4; ++j)
            #pragma unroll
            for (int r = 0; r < 4; ++r){
                int rowg = n0 + wr + i*16 + quad*4 + r;
                int o = j*16 + m16;
                if (rowg < N_NODES) out[(long)rowg*64 + o] = acc[i][j][r] + cvec[o];
            }
}

extern "C" void kernel_launch(void* const* d_in, const int* in_sizes, int n_in,
                              void* d_out, int out_size, void* d_ws, size_t ws_size,
                              hipStream_t stream) {
    const float* feats = (const float*)d_in[0];
    const int*   src   = (const int*)  d_in[1];
    const int*   dst   = (const int*)  d_in[2];
    const float* W0    = (const float*)d_in[3];
    const float* b0    = (const float*)d_in[4];
    const float* W1    = (const float*)d_in[5];
    const float* b1    = (const float*)d_in[6];
    const float* W2    = (const float*)d_in[7];
    const float* b2    = (const float*)d_in[8];
    const float* fcW   = (const float*)d_in[9];
    const float* fcb   = (const float*)d_in[10];
    const float* gamma = (const float*)d_in[11];
    const float* beta  = (const float*)d_in[12];
    const float* q     = (const float*)d_in[13];
    float* out = (float*)d_out;

    char* ws = (char*)d_ws;
    size_t off = 0;
    auto alloc = [&](size_t bytes) -> char* {
        char* p = ws + off;
        off = (off + bytes + 511) & ~(size_t)511;
        return p;
    };
    uint*   hist    = (uint*)  alloc((size_t)NSLICE * NGRP * 4);
    uchar*  pfx     = (uchar*) alloc((size_t)NSLICE * N_NODES);
    uchar*  ctot    = (uchar*) alloc((size_t)16 * N_NODES);
    uchar*  cbase   = (uchar*) alloc((size_t)16 * N_NODES);
    uchar*  rank8   = (uchar*) alloc((size_t)N_EDGES);
    int*    deg     = (int*)   alloc((size_t)N_NODES * 4);
    int*    rowptr  = (int*)   alloc((size_t)N_NODES * 4);
    float*  nrm     = (float*) alloc((size_t)N_NODES * 4);
    int*    counter = (int*)   alloc(256);
    int*    csr     = (int*)   alloc((size_t)N_EDGES * 4);
    ushort* Hx      = (ushort*)alloc((size_t)N_NODES * 64 * 2);
    ushort* HsB     = (ushort*)alloc((size_t)N_NODES * 64 * 2);
    ushort* H       = (ushort*)alloc((size_t)N_NODES * KDIM * 2);
    ushort* MT      = (ushort*)alloc((size_t)HIDDEN * KDIM * 2);
    float*  Bc      = (float*) alloc((size_t)HIDDEN * 4);
    float*  msum    = (float*) alloc((size_t)KDIM * 4);
    uint*   P       = (uint*)  alloc((size_t)NCHUNK * PPB * 4);
    float*  SP      = (float*) alloc((size_t)NSPLIT * NPAIR * 256 * 4);
    float*  C       = (float*) alloc((size_t)SDIM * 4);
    float*  V       = (float*) alloc((size_t)HIDDEN * KDIM * 4);
    float*  rr      = (float*) alloc((size_t)HIDDEN * 4);
    float*  cvec    = (float*) alloc((size_t)64 * 4);
    ushort* GT      = (ushort*)alloc((size_t)64 * KDIM * 2);
    (void)ws_size; (void)n_in; (void)in_sizes; (void)out_size;

    hipMemsetAsync(counter, 0, 256, stream);
    hipMemsetAsync(msum, 0, (size_t)KDIM * 4, stream);

    k_hist  <<<NSLICE, 1024, 0, stream>>>(dst, hist, rank8);
    dim3 saGrid((NGRP + 255)/256, 16);
    k_scanA <<<saGrid, 256, 0, stream>>>(hist, pfx, ctot);
    k_scan2 <<<(NGRP + 255)/256, 256, 0, stream>>>(ctot, cbase, deg, nrm);
    k_rowptr<<<(N_NODES + 255)/256, 256, 0, stream>>>(deg, rowptr, counter);
    k_cast  <<<(N_NODES*16 + 255)/256, 256, 0, stream>>>(feats, nrm, Hx);
    k_scatter<<<8*NSLICE, 256, 0, stream>>>(src, dst, rowptr, pfx, cbase, rank8, csr);

    int aggGrid = (N_NODES + 7) / 8;
    k_agg<true> <<<aggGrid, 256, 0, stream>>>(Hx,  H, 0,   HsB, rowptr, deg, nrm, csr);
    k_agg<true> <<<aggGrid, 256, 0, stream>>>(HsB, H, 64,  Hx,  rowptr, deg, nrm, csr);
    k_agg<false><<<aggGrid, 256, 0, stream>>>(Hx,  H, 128, HsB, rowptr, deg, nrm, csr);

    k_prepM<<<HIDDEN, KDIM, 0, stream>>>(W0, W1, W2, fcW, MT);
    k_bias <<<2, 256, 0, stream>>>(b0, b1, b2, fcW, fcb, Bc);

    k_hth   <<<NCHUNK, 256, 0, stream>>>(H, P, msum);
    dim3 rGrid(PPB/256, NSPLIT);
    k_reduce<<<rGrid, 256, 0, stream>>>(P, SP);
    k_finC  <<<NPAIR, 256, 0, stream>>>(SP, msum, C);
    k_cv    <<<HIDDEN, KDIM, 0, stream>>>(C, MT, V);
    k_solve2<<<1, HIDDEN, 0, stream>>>(V, MT, msum, Bc, gamma, beta, q, rr, cvec);
    k_buildG<<<64, KDIM, 0, stream>>>(MT, rr, q, GT);

    k_outgemm<<<NCHUNK, 256, 0, stream>>>(H, GT, cvec, out);
}